// Round 5
// baseline (534.551 us; speedup 1.0000x reference)
//
#include <hip/hip_runtime.h>
#include <string.h>

#define H 128
#define NTYPES 28
#define CNT_BYTES_PER_CYCLE 32   // 28 byte counters + 4 pad, dword-packed

typedef float f32x4 __attribute__((ext_vector_type(4)));

// ---- count: one incidence -> +1 on byte counter cnt[cycle][type] ----
// Fire-and-forget 32-bit atomics. Pinned at ~90 us by R1 differential
// (701.6 - 416.6 - 365.4). Returning-atomic binned variant: 416 us (R1),
// do not revisit.
__global__ void count_kernel(const int* __restrict__ a2c,
                             const int* __restrict__ x,
                             unsigned* __restrict__ cnt,
                             int n_inc) {
    int i = (blockIdx.x * blockDim.x + threadIdx.x) * 4;
    if (i + 3 < n_inc) {
        int4 at = *(const int4*)(a2c + i);
        int4 cy = *(const int4*)(a2c + n_inc + i);
        int t0 = x[at.x], t1 = x[at.y], t2 = x[at.z], t3 = x[at.w];
        atomicAdd(&cnt[cy.x * 8 + (t0 >> 2)], 1u << (8 * (t0 & 3)));
        atomicAdd(&cnt[cy.y * 8 + (t1 >> 2)], 1u << (8 * (t1 & 3)));
        atomicAdd(&cnt[cy.z * 8 + (t2 >> 2)], 1u << (8 * (t2 & 3)));
        atomicAdd(&cnt[cy.w * 8 + (t3 >> 2)], 1u << (8 * (t3 & 3)));
    } else {
        for (int e = i; e < n_inc; ++e) {
            int atom = a2c[e];
            int cycv = a2c[n_inc + e];
            int t = x[atom];
            atomicAdd(&cnt[cycv * 8 + (t >> 2)], 1u << (8 * (t & 3)));
        }
    }
}

// ---- expand2: one wave per PAIR of cycles (unchanged from R3) ----
// ATTRIBUTION ROUND (retry; R4 was an infra failure): launched 1 + 3 times;
// the 3 extra passes write cold ws scratch. (dur - 368.4)/3 = expand's true
// marginal cost. World (a): ~50 us -> dur ~515, expand is at its floor and
// harness fixed overhead ~230 us. World (b): ~118 us -> dur ~720. Removed
// next round either way.
__global__ __launch_bounds__(256) void expand2_kernel(
        const unsigned char* __restrict__ cnt,
        const float* __restrict__ emb,
        float* __restrict__ out,
        int num_cycles) {
    __shared__ __align__(16) float lds[NTYPES * H];
    for (int i = threadIdx.x; i < NTYPES * H; i += blockDim.x) lds[i] = emb[i];
    __syncthreads();
    const f32x4* l4 = (const f32x4*)lds;

    const int lane = threadIdx.x & 63;
    const int half = lane >> 5;
    const int hl   = lane & 31;
    const int w    = blockIdx.x * (blockDim.x >> 6) + (threadIdx.x >> 6);
    const int nw   = gridDim.x * (blockDim.x >> 6);

    const int P   = (num_cycles + 1) >> 1;        // cycle pairs
    const int ppw = (P + nw - 1) / nw;            // pairs per wave (contiguous)
    int p0 = w * ppw;
    int p1 = p0 + ppw; if (p1 > P) p1 = P;
    if (p0 >= p1) return;

    unsigned b0 = cnt[(size_t)p0 * 64 + lane];
    unsigned b1 = (p0 + 1 < p1) ? cnt[(size_t)(p0 + 1) * 64 + lane] : 0u;

    for (int p = p0; p < p1; ++p) {
        unsigned b = b0;
        b0 = b1;
        b1 = (p + 2 < p1) ? cnt[(size_t)(p + 2) * 64 + lane] : 0u;

        int c = 2 * p + half;
        unsigned long long bal = __ballot(b != 0);
        unsigned m = (half ? (unsigned)(bal >> 32) : (unsigned)bal) & 0x0FFFFFFFu;
        if (c >= num_cycles) m = 0;               // odd-tail guard

        f32x4 acc = {0.f, 0.f, 0.f, 0.f};
        while (m) {
            int t = __builtin_ctz(m);
            m &= m - 1;
            float f = (float)(unsigned)__shfl((int)b, t + (half << 5));
            f32x4 wv = l4[t * 32 + hl];           // ds_read_b128, conflict-free
            acc += f * wv;
        }
        if (c < num_cycles) {
            f32x4* dst = (f32x4*)(out + (size_t)c * H) + hl;
            *dst = acc;
        }
    }
}

// ---- fallback (ws too small): direct atomic scatter ----
__global__ void scatter_direct_kernel(const int* __restrict__ a2c,
                                      const int* __restrict__ x,
                                      const float* __restrict__ emb,
                                      float* __restrict__ out,
                                      int n_inc) {
    int gid = blockIdx.x * blockDim.x + threadIdx.x;
    int e  = gid >> 5;
    int ch = gid & 31;
    if (e >= n_inc) return;
    int atom = a2c[e];
    int cyc  = a2c[n_inc + e];
    int t    = x[atom];
    const float4 w = ((const float4*)(emb + t * H))[ch];
    float* o = out + (size_t)cyc * H + ch * 4;
    atomicAdd(o + 0, w.x);
    atomicAdd(o + 1, w.y);
    atomicAdd(o + 2, w.z);
    atomicAdd(o + 3, w.w);
}

__global__ void zero_u4_kernel(uint4* __restrict__ p, int n4) {
    int i = blockIdx.x * blockDim.x + threadIdx.x;
    if (i < n4) p[i] = make_uint4(0u, 0u, 0u, 0u);
}

extern "C" void kernel_launch(void* const* d_in, const int* in_sizes, int n_in,
                              void* d_out, int out_size, void* d_ws, size_t ws_size,
                              hipStream_t stream) {
    const int*   x    = (const int*)d_in[0];
    const int*   a2c  = (const int*)d_in[1];
    const float* emb  = (const float*)d_in[2];
    float*       out  = (float*)d_out;

    const int n_inc      = in_sizes[1] / 2;
    const int num_cycles = out_size / H;
    const size_t cnt_bytes = (size_t)num_cycles * CNT_BYTES_PER_CYCLE;

    if (ws_size >= cnt_bytes) {
        unsigned* cnt = (unsigned*)d_ws;
        hipMemsetAsync(d_ws, 0, cnt_bytes, stream);
        int nthreads = (n_inc + 3) / 4;
        count_kernel<<<(nthreads + 255) / 256, 256, 0, stream>>>(a2c, x, cnt, n_inc);
        expand2_kernel<<<2048, 256, 0, stream>>>(
            (const unsigned char*)cnt, emb, out, num_cycles);

        // ---- measurement passes: 3x identical expand into cold ws scratch ----
        // (dur - 368.4)/3 = expand marginal cost. Serial on one stream: additive.
        const size_t scratch_off = (cnt_bytes + 255) & ~(size_t)255;
        if (ws_size >= scratch_off + (size_t)out_size) {
            float* scratch = (float*)((char*)d_ws + scratch_off);
            expand2_kernel<<<2048, 256, 0, stream>>>(
                (const unsigned char*)cnt, emb, scratch, num_cycles);
            expand2_kernel<<<2048, 256, 0, stream>>>(
                (const unsigned char*)cnt, emb, scratch, num_cycles);
            expand2_kernel<<<2048, 256, 0, stream>>>(
                (const unsigned char*)cnt, emb, scratch, num_cycles);
        }
    } else {
        int n4 = out_size / 4;
        zero_u4_kernel<<<(n4 + 255) / 256, 256, 0, stream>>>((uint4*)d_out, n4);
        long long total = (long long)n_inc * 32;
        int blocks = (int)((total + 255) / 256);
        scatter_direct_kernel<<<blocks, 256, 0, stream>>>(a2c, x, emb, out, n_inc);
    }
}

// Round 7
// 351.737 us; speedup vs baseline: 1.5197x; 1.5197x over previous
//
#include <hip/hip_runtime.h>
#include <string.h>

#define H 128
#define NTYPES 28
#define CNT_BYTES_PER_CYCLE 32   // 28 byte counters + 4 pad, dword-packed

#define SHIFT 11                 // cycles per bucket = 2048
#define MAXB  256                // max pass-1 blocks AND max buckets
#define CHUNK 8192               // incidences per pass-1 block

typedef float f32x4 __attribute__((ext_vector_type(4)));

// ---- pass 1: partition incidence keys into coarse cycle-buckets ----
// NO global returning atomics (R1 lesson). Per-block LDS count -> scan ->
// LDS-cursor placement into the block's OWN disjoint global window.
// R6 BUG FIXED: cursor must be seeded with the GLOBAL start (base + excl);
// R6 seeded the chunk-local offset, so all blocks clobbered keys[0..8192).
__global__ __launch_bounds__(256) void partition_kernel(
        const int* __restrict__ a2c, const int* __restrict__ x,
        unsigned* __restrict__ keys,
        unsigned* __restrict__ tstart, unsigned* __restrict__ tlen,
        int n_inc, int nbkt) {
    __shared__ unsigned hcnt[MAXB];
    __shared__ unsigned hoff[MAXB];
    const int tid  = threadIdx.x;
    const int base = blockIdx.x * CHUNK;
    const int lim  = min(base + CHUNK, n_inc);

    hcnt[tid] = 0;
    __syncthreads();

    // round A: bucket counts (fire-and-forget LDS atomics)
    for (int q = 0; q < CHUNK / 1024; ++q) {
        int off = base + q * 1024 + tid * 4;
        if (off + 3 < lim) {
            int4 cy = *(const int4*)(a2c + n_inc + off);
            atomicAdd(&hcnt[(unsigned)cy.x >> SHIFT], 1u);
            atomicAdd(&hcnt[(unsigned)cy.y >> SHIFT], 1u);
            atomicAdd(&hcnt[(unsigned)cy.z >> SHIFT], 1u);
            atomicAdd(&hcnt[(unsigned)cy.w >> SHIFT], 1u);
        } else {
            for (int e = off; e < lim && e < off + 4; ++e)
                atomicAdd(&hcnt[(unsigned)a2c[n_inc + e] >> SHIFT], 1u);
        }
    }
    __syncthreads();

    // exclusive scan over 256 bucket counts (Hillis-Steele)
    unsigned v = hcnt[tid];
    hoff[tid] = v;
    __syncthreads();
    for (int d = 1; d < MAXB; d <<= 1) {
        unsigned u = (tid >= d) ? hoff[tid - d] : 0u;
        __syncthreads();
        hoff[tid] += u;
        __syncthreads();
    }
    unsigned excl = hoff[tid] - v;

    // run table: (global start, len) of this block's run for each bucket
    if (tid < nbkt) {
        tstart[tid * MAXB + blockIdx.x] = (unsigned)base + excl;
        tlen  [tid * MAXB + blockIdx.x] = v;
    }
    hoff[tid] = (unsigned)base + excl;   // GLOBAL placement cursor (the fix)
    __syncthreads();

    // round B: place keys (LDS-returning cursor, <=8192 ops/block)
    for (int q = 0; q < CHUNK / 1024; ++q) {
        int off = base + q * 1024 + tid * 4;
        if (off + 3 < lim) {
            int4 at = *(const int4*)(a2c + off);
            int4 cy = *(const int4*)(a2c + n_inc + off);
            int t0 = x[at.x], t1 = x[at.y], t2 = x[at.z], t3 = x[at.w];
            unsigned p;
            p = atomicAdd(&hoff[(unsigned)cy.x >> SHIFT], 1u);
            keys[p] = ((unsigned)cy.x << 5) | (unsigned)t0;
            p = atomicAdd(&hoff[(unsigned)cy.y >> SHIFT], 1u);
            keys[p] = ((unsigned)cy.y << 5) | (unsigned)t1;
            p = atomicAdd(&hoff[(unsigned)cy.z >> SHIFT], 1u);
            keys[p] = ((unsigned)cy.z << 5) | (unsigned)t2;
            p = atomicAdd(&hoff[(unsigned)cy.w >> SHIFT], 1u);
            keys[p] = ((unsigned)cy.w << 5) | (unsigned)t3;
        } else {
            for (int e = off; e < lim && e < off + 4; ++e) {
                unsigned key = ((unsigned)a2c[n_inc + e] << 5)
                             | (unsigned)x[a2c[e]];
                unsigned p = atomicAdd(&hoff[key >> (5 + SHIFT)], 1u);
                keys[p] = key;
            }
        }
    }
}

// ---- pass 2: one block per bucket -> 64 KB LDS histogram -> dense cnt ----
__global__ __launch_bounds__(256) void bucket_hist_kernel(
        const unsigned* __restrict__ keys,
        const unsigned* __restrict__ tstart, const unsigned* __restrict__ tlen,
        unsigned* __restrict__ cnt, int num_cycles, int nblk1) {
    __shared__ unsigned hist[(1 << SHIFT) * 8];   // 64 KB
    __shared__ unsigned rstart[MAXB];
    __shared__ unsigned rexcl[MAXB];
    __shared__ unsigned plen[MAXB];
    const int tid = threadIdx.x;
    const int b   = blockIdx.x;

    for (int k = tid; k < (1 << SHIFT) * 8; k += 256) hist[k] = 0;
    unsigned L = (tid < nblk1) ? tlen[b * MAXB + tid] : 0u;
    rstart[tid] = (tid < nblk1) ? tstart[b * MAXB + tid] : 0u;
    plen[tid] = L;
    __syncthreads();
    for (int d = 1; d < MAXB; d <<= 1) {
        unsigned u = (tid >= d) ? plen[tid - d] : 0u;
        __syncthreads();
        plen[tid] += u;
        __syncthreads();
    }
    rexcl[tid] = plen[tid] - L;
    __syncthreads();
    const unsigned T = plen[MAXB - 1];

    for (unsigned g = tid; g < T; g += 256) {
        int lo = 0, hi = MAXB - 1;        // invariant: plen[hi] > g
        while (lo < hi) {
            int mid = (lo + hi) >> 1;
            if (plen[mid] > g) hi = mid; else lo = mid + 1;
        }
        unsigned key = keys[rstart[lo] + (g - rexcl[lo])];
        unsigned lc  = (key >> 5) & ((1u << SHIFT) - 1u);
        unsigned t   = key & 31u;
        atomicAdd(&hist[lc * 8 + (t >> 2)], 1u << (8 * (t & 3)));
    }
    __syncthreads();

    const int cb  = b << SHIFT;
    int ncyc = num_cycles - cb;
    if (ncyc > (1 << SHIFT)) ncyc = 1 << SHIFT;
    const int ndw = ncyc * 8;
    for (int k = tid; k < ndw; k += 256)
        cnt[(size_t)cb * 8 + k] = hist[k];
}

// ---- legacy count (fallback): fire-and-forget global atomics, ~90 us ----
__global__ void count_kernel(const int* __restrict__ a2c,
                             const int* __restrict__ x,
                             unsigned* __restrict__ cnt,
                             int n_inc) {
    int i = (blockIdx.x * blockDim.x + threadIdx.x) * 4;
    if (i + 3 < n_inc) {
        int4 at = *(const int4*)(a2c + i);
        int4 cy = *(const int4*)(a2c + n_inc + i);
        int t0 = x[at.x], t1 = x[at.y], t2 = x[at.z], t3 = x[at.w];
        atomicAdd(&cnt[cy.x * 8 + (t0 >> 2)], 1u << (8 * (t0 & 3)));
        atomicAdd(&cnt[cy.y * 8 + (t1 >> 2)], 1u << (8 * (t1 & 3)));
        atomicAdd(&cnt[cy.z * 8 + (t2 >> 2)], 1u << (8 * (t2 & 3)));
        atomicAdd(&cnt[cy.w * 8 + (t3 >> 2)], 1u << (8 * (t3 & 3)));
    } else {
        for (int e = i; e < n_inc; ++e) {
            int t = x[a2c[e]];
            atomicAdd(&cnt[a2c[n_inc + e] * 8 + (t >> 2)], 1u << (8 * (t & 3)));
        }
    }
}

// ---- expand2: one wave per PAIR of cycles (measured 55 us, near floor) ----
__global__ __launch_bounds__(256) void expand2_kernel(
        const unsigned char* __restrict__ cnt,
        const float* __restrict__ emb,
        float* __restrict__ out,
        int num_cycles) {
    __shared__ __align__(16) float lds[NTYPES * H];
    for (int i = threadIdx.x; i < NTYPES * H; i += blockDim.x) lds[i] = emb[i];
    __syncthreads();
    const f32x4* l4 = (const f32x4*)lds;

    const int lane = threadIdx.x & 63;
    const int half = lane >> 5;
    const int hl   = lane & 31;
    const int w    = blockIdx.x * (blockDim.x >> 6) + (threadIdx.x >> 6);
    const int nw   = gridDim.x * (blockDim.x >> 6);

    const int P   = (num_cycles + 1) >> 1;
    const int ppw = (P + nw - 1) / nw;
    int p0 = w * ppw;
    int p1 = p0 + ppw; if (p1 > P) p1 = P;
    if (p0 >= p1) return;

    unsigned b0 = cnt[(size_t)p0 * 64 + lane];
    unsigned b1 = (p0 + 1 < p1) ? cnt[(size_t)(p0 + 1) * 64 + lane] : 0u;

    for (int p = p0; p < p1; ++p) {
        unsigned b = b0;
        b0 = b1;
        b1 = (p + 2 < p1) ? cnt[(size_t)(p + 2) * 64 + lane] : 0u;

        int c = 2 * p + half;
        unsigned long long bal = __ballot(b != 0);
        unsigned m = (half ? (unsigned)(bal >> 32) : (unsigned)bal) & 0x0FFFFFFFu;
        if (c >= num_cycles) m = 0;

        f32x4 acc = {0.f, 0.f, 0.f, 0.f};
        while (m) {
            int t = __builtin_ctz(m);
            m &= m - 1;
            float f = (float)(unsigned)__shfl((int)b, t + (half << 5));
            f32x4 wv = l4[t * 32 + hl];
            acc += f * wv;
        }
        if (c < num_cycles) {
            f32x4* dst = (f32x4*)(out + (size_t)c * H) + hl;
            *dst = acc;
        }
    }
}

// ---- fallback (ws too small): direct atomic scatter ----
__global__ void scatter_direct_kernel(const int* __restrict__ a2c,
                                      const int* __restrict__ x,
                                      const float* __restrict__ emb,
                                      float* __restrict__ out,
                                      int n_inc) {
    int gid = blockIdx.x * blockDim.x + threadIdx.x;
    int e  = gid >> 5;
    int ch = gid & 31;
    if (e >= n_inc) return;
    int t = x[a2c[e]];
    int cyc = a2c[n_inc + e];
    const float4 w = ((const float4*)(emb + t * H))[ch];
    float* o = out + (size_t)cyc * H + ch * 4;
    atomicAdd(o + 0, w.x);
    atomicAdd(o + 1, w.y);
    atomicAdd(o + 2, w.z);
    atomicAdd(o + 3, w.w);
}

__global__ void zero_u4_kernel(uint4* __restrict__ p, int n4) {
    int i = blockIdx.x * blockDim.x + threadIdx.x;
    if (i < n4) p[i] = make_uint4(0u, 0u, 0u, 0u);
}

extern "C" void kernel_launch(void* const* d_in, const int* in_sizes, int n_in,
                              void* d_out, int out_size, void* d_ws, size_t ws_size,
                              hipStream_t stream) {
    const int*   x    = (const int*)d_in[0];
    const int*   a2c  = (const int*)d_in[1];
    const float* emb  = (const float*)d_in[2];
    float*       out  = (float*)d_out;

    const int n_inc      = in_sizes[1] / 2;
    const int num_cycles = out_size / H;
    const size_t cnt_bytes = (size_t)num_cycles * CNT_BYTES_PER_CYCLE;

    const int nbkt  = (num_cycles > 0) ? (((num_cycles - 1) >> SHIFT) + 1) : 0;
    const int nblk1 = (n_inc + CHUNK - 1) / CHUNK;
    const size_t keys_bytes = ((size_t)n_inc * 4 + 255) & ~(size_t)255;
    const size_t tab_bytes  = 2 * (size_t)MAXB * MAXB * 4;       // 512 KB
    const size_t cnt_off    = (keys_bytes + tab_bytes + 255) & ~(size_t)255;
    const size_t need_part  = cnt_off + cnt_bytes;

    if (num_cycles > 0 && n_inc > 0 && nbkt <= MAXB && nblk1 <= MAXB &&
        ws_size >= need_part) {
        char* wsb = (char*)d_ws;
        unsigned* keys   = (unsigned*)wsb;
        unsigned* tstart = (unsigned*)(wsb + keys_bytes);
        unsigned* tlen   = tstart + (size_t)MAXB * MAXB;
        unsigned* cnt    = (unsigned*)(wsb + cnt_off);

        partition_kernel<<<nblk1, 256, 0, stream>>>(
            a2c, x, keys, tstart, tlen, n_inc, nbkt);
        bucket_hist_kernel<<<nbkt, 256, 0, stream>>>(
            keys, tstart, tlen, cnt, num_cycles, nblk1);
        expand2_kernel<<<2048, 256, 0, stream>>>(
            (const unsigned char*)cnt, emb, out, num_cycles);
    } else if (ws_size >= cnt_bytes) {
        unsigned* cnt = (unsigned*)d_ws;
        hipMemsetAsync(d_ws, 0, cnt_bytes, stream);
        int nthreads = (n_inc + 3) / 4;
        count_kernel<<<(nthreads + 255) / 256, 256, 0, stream>>>(a2c, x, cnt, n_inc);
        expand2_kernel<<<2048, 256, 0, stream>>>(
            (const unsigned char*)cnt, emb, out, num_cycles);
    } else {
        int n4 = out_size / 4;
        zero_u4_kernel<<<(n4 + 255) / 256, 256, 0, stream>>>((uint4*)d_out, n4);
        long long total = (long long)n_inc * 32;
        int blocks = (int)((total + 255) / 256);
        scatter_direct_kernel<<<blocks, 256, 0, stream>>>(a2c, x, emb, out, n_inc);
    }
}